// Round 4
// baseline (198.939 us; speedup 1.0000x reference)
//
#include <hip/hip_runtime.h>

#define DEV_INLINE __device__ __forceinline__

// Native clang vector type — required by __builtin_nontemporal_store
// (HIP's float4 is a class and is rejected).
typedef float vfloat4 __attribute__((ext_vector_type(4)));

// softplus(v) = max(v,0) + ln2 * log2(1 + 2^(-|v|*log2e))
// Raw v_exp_f32 / v_log_f32 (quarter-rate), mul/fma fused: 6 VALU instrs.
DEV_INLINE float softplus_f(float v) {
#if __has_builtin(__builtin_amdgcn_logf) && __has_builtin(__builtin_amdgcn_exp2f)
    float e = __builtin_amdgcn_exp2f(fabsf(v) * -1.44269504f);
    float l = __builtin_amdgcn_logf(1.0f + e);            // v_log_f32 = log2
    return fmaf(0.69314718f, l, fmaxf(v, 0.0f));
#else
    return fmaxf(v, 0.0f) + __logf(1.0f + __expf(-fabsf(v)));
#endif
}

// One thread = one row. Output staged through a PER-WAVE LDS region (9 KB)
// so each wave streams its 64 rows to global as soon as its own compute is
// done -- no __syncthreads, waves in a block don't couple (R2 used a block
// barrier: compute & store phases serialized across all 4 waves).
// DS ordering: explicit s_waitcnt lgkmcnt(0) + memory clobber between the
// staging writes and the readback makes the in-wave RAW safe.
__global__ __launch_bounds__(256) void pb_kernel(
    const float* __restrict__ x,
    const float* __restrict__ W_in, const float* __restrict__ b_in,
    const float* __restrict__ W1,   const float* __restrict__ b1,
    const float* __restrict__ W2,   const float* __restrict__ b2,
    const float* __restrict__ W3,   const float* __restrict__ b3,
    const float* __restrict__ W4,   const float* __restrict__ b4,
    const float* __restrict__ W_out,const float* __restrict__ b_out,
    float* __restrict__ out, int n_rows)
{
    __shared__ vfloat4 sbuf[4][64 * 9];   // 36 KB: per-wave 9 KB regions

    const int tid  = threadIdx.x;
    const int wave = tid >> 6;
    const int lane = tid & 63;
    const int row_raw = blockIdx.x * 256 + tid;
    const int row = row_raw < n_rows ? row_raw : n_rows - 1;   // grid is exact

    // ---- load one row of x (6 floats = three float2 loads) ----
    const float2* xv = (const float2*)(x + (size_t)row * 6);
    float2 p0 = xv[0], p1 = xv[1], p2 = xv[2];
    const float xin[6] = { p0.x, p0.y, p1.x, p1.y, p2.x, p2.y };

    // ---- input layer 6 -> 8 ----
    float y[8];
    #pragma unroll
    for (int o = 0; o < 8; ++o) {
        float acc = b_in[o];
        #pragma unroll
        for (int i = 0; i < 6; ++i)
            acc = fmaf(W_in[o * 6 + i], xin[i], acc);
        y[o] = softplus_f(acc);
    }

    // ---- 4 hidden layers 8 -> 8 ----
    const float* Ws[4] = { W1, W2, W3, W4 };
    const float* bs[4] = { b1, b2, b3, b4 };
    #pragma unroll
    for (int l = 0; l < 4; ++l) {
        const float* __restrict__ W = Ws[l];
        const float* __restrict__ b = bs[l];
        float t[8];
        #pragma unroll
        for (int o = 0; o < 8; ++o) {
            float acc = b[o];
            #pragma unroll
            for (int i = 0; i < 8; ++i)
                acc = fmaf(W[o * 8 + i], y[i], acc);
            t[o] = softplus_f(acc);
        }
        #pragma unroll
        for (int o = 0; o < 8; ++o) y[o] = t[o];
    }

    // ---- output layer 8 -> 15 ----
    float u[15];
    #pragma unroll
    for (int o = 0; o < 15; ++o) {
        float acc = b_out[o];
        #pragma unroll
        for (int i = 0; i < 8; ++i)
            acc = fmaf(W_out[o * 8 + i], y[i], acc);
        u[o] = acc;
    }

    // ---- assemble antisymmetric 6x6 ----
    float L[36];
    #pragma unroll
    for (int i = 0; i < 36; ++i) L[i] = 0.0f;
    {
        int k = 0;
        #pragma unroll
        for (int i = 0; i < 6; ++i) {
            #pragma unroll
            for (int j = i + 1; j < 6; ++j) {
                L[i * 6 + j] = u[k];
                L[j * 6 + i] = -u[k];
                ++k;
            }
        }
    }

    // ---- stage to this wave's LDS region ----
    // lane l, chunk m -> bank group (l*9+m)%8 = (l+m)%8: uniform over the
    // wave, so each b128 access hits the 32 banks evenly (minimum cycles).
    vfloat4* ws = sbuf[wave];
    #pragma unroll
    for (int m = 0; m < 9; ++m) {
        vfloat4 v = { L[4 * m + 0], L[4 * m + 1], L[4 * m + 2], L[4 * m + 3] };
        ws[lane * 9 + m] = v;
    }

    // In-wave fence: drain DS writes, block compiler reordering.
    asm volatile("s_waitcnt lgkmcnt(0)" ::: "memory");

    // ---- wave-coalesced streaming store: 9 KB contiguous per wave ----
    // Each wave instruction stores 64 lanes x 16 B = 1 KiB contiguous.
    // Nontemporal: output is never re-read, evict early from L2/LLC.
    vfloat4* dst = (vfloat4*)out + (size_t)blockIdx.x * (256 * 9) + wave * (64 * 9);
    #pragma unroll
    for (int q = 0; q < 9; ++q) {
        vfloat4 v = ws[q * 64 + lane];
        __builtin_nontemporal_store(v, &dst[q * 64 + lane]);
    }
}

extern "C" void kernel_launch(void* const* d_in, const int* in_sizes, int n_in,
                              void* d_out, int out_size, void* d_ws, size_t ws_size,
                              hipStream_t stream) {
    const float* x     = (const float*)d_in[0];
    const float* W_in  = (const float*)d_in[1];
    const float* b_in  = (const float*)d_in[2];
    const float* W1    = (const float*)d_in[3];
    const float* b1    = (const float*)d_in[4];
    const float* W2    = (const float*)d_in[5];
    const float* b2    = (const float*)d_in[6];
    const float* W3    = (const float*)d_in[7];
    const float* b3    = (const float*)d_in[8];
    const float* W4    = (const float*)d_in[9];
    const float* b4    = (const float*)d_in[10];
    const float* W_out = (const float*)d_in[11];
    const float* b_out = (const float*)d_in[12];
    float* out = (float*)d_out;

    const int n_rows = in_sizes[0] / 6;           // B*T = 1,048,576 (mult of 256)
    const int block = 256;
    const int grid = (n_rows + block - 1) / block;

    hipLaunchKernelGGL(pb_kernel, dim3(grid), dim3(block), 0, stream,
                       x, W_in, b_in, W1, b1, W2, b2, W3, b3, W4, b4,
                       W_out, b_out, out, n_rows);
}